// Round 2
// baseline (1675.904 us; speedup 1.0000x reference)
//
#include <hip/hip_runtime.h>
#include <math.h>

// Problem constants (reference: S,B,I,H = 1024,512,5,32; G=4H=128)
#define S_LEN 1024
#define BATCH 512
#define HID   32

#define LOG2E 1.44269504088896340736f

__device__ __forceinline__ float fast_rcp(float x) { return __builtin_amdgcn_rcpf(x); }
__device__ __forceinline__ float fast_exp2(float x) { return __builtin_amdgcn_exp2f(x); }

// Broadcast lane k's value to all lanes via v_readlane (VALU + SGPR operand,
// does NOT touch the LDS pipe). k is compile-time constant after unroll.
__device__ __forceinline__ float bcast(float v, int k) {
    return __int_as_float(__builtin_amdgcn_readlane(__float_as_int(v), k));
}

// LSTM pointwise tail. accA/accB pre-scaled by log2e (accB by 2*log2e on low
// half, where it holds the g-gate). Lane layout (round-0 scheme):
//   lane l, j=l&31: low half owns rows gA=l (i_j) and gB=l+64 (g_j);
//   high half owns rows gA=l (f_j) and gB=l+64 (o_j).
// One shfl_xor(32) pair gives every lane all 4 gates of unit j.
__device__ __forceinline__ void lstm_tail(float accA, float accB, bool lowHalf,
                                          float c, float& c_out, float& h_out)
{
    float pA = __shfl_xor(accA, 32);
    float pB = __shfl_xor(accB, 32);
    float yi = lowHalf ? accA : pA;
    float yf = lowHalf ? pA : accA;
    float yg = lowHalf ? accB : pB;   // scaled by 2*log2e
    float yo = lowHalf ? pB : accB;
    float gi = fast_rcp(1.0f + fast_exp2(-yi));
    float gf = fast_rcp(1.0f + fast_exp2(-yf));
    float sg = fast_rcp(1.0f + fast_exp2(-yg));
    float go = fast_rcp(1.0f + fast_exp2(-yo));
    float gg = 2.0f * sg - 1.0f;      // tanh(g) = 2*sigma(2g) - 1
    float cn = gf * c + gi * gg;
    float e  = fast_exp2(-2.0f * LOG2E * fabsf(cn));
    float tc = copysignf((1.0f - e) * fast_rcp(1.0f + e), cn);
    c_out = cn;
    h_out = go * tc;                  // redundant in both halves (by design)
}

// Load one 32-float weight row into registers, pre-scaled.
#define LOADROW(dst, base, row, sc)                                            \
    {                                                                          \
        const float4* W_ = reinterpret_cast<const float4*>((base) +            \
                                                    (size_t)(row) * HID);      \
        _Pragma("unroll")                                                      \
        for (int k4 = 0; k4 < 8; ++k4) {                                       \
            float4 v_ = W_[k4];                                                \
            dst[4 * k4 + 0] = v_.x * (sc);                                     \
            dst[4 * k4 + 1] = v_.y * (sc);                                     \
            dst[4 * k4 + 2] = v_.z * (sc);                                     \
            dst[4 * k4 + 3] = v_.w * (sc);                                     \
        }                                                                      \
    }

// Fused 3-layer LSTM: ONE WAVE per batch element, all three layers in-wave.
// Zero LDS, zero barriers. Software pipeline: at tick t, layer l is at step
// t-l. All gate dots read the PREVIOUS tick's h registers (broadcast via
// readlane), then states commit under uniform (scalar) guards.
// Weights: 330 VGPRs/lane (6 recurrent rows + 4 input rows + 2 x-rows).
__global__ __launch_bounds__(64)
void lstm3_fused(const float* __restrict__ x,
                 const float* __restrict__ Wih0, const float* __restrict__ Whh0,
                 const float* __restrict__ bih0, const float* __restrict__ bhh0,
                 const float* __restrict__ Wih1, const float* __restrict__ Whh1,
                 const float* __restrict__ bih1, const float* __restrict__ bhh1,
                 const float* __restrict__ Wih2, const float* __restrict__ Whh2,
                 const float* __restrict__ bih2, const float* __restrict__ bhh2,
                 float* __restrict__ hseq)
{
    const int b = blockIdx.x;
    const int l = threadIdx.x & 63;
    const int j = l & 31;
    const bool lowHalf = (l < 32);
    const int gA = l;
    const int gB = l + 64;
    const float sA = LOG2E;
    const float sB = lowHalf ? (2.0f * LOG2E) : LOG2E;  // g rows get 2*log2e

    // ---- weights to registers (shared across all ticks) ----
    float whA0[HID], whB0[HID], whA1[HID], whB1[HID], whA2[HID], whB2[HID];
    float wiA1[HID], wiB1[HID], wiA2[HID], wiB2[HID];
    float wxA[5], wxB[5];

    LOADROW(whA0, Whh0, gA, sA); LOADROW(whB0, Whh0, gB, sB);
    LOADROW(whA1, Whh1, gA, sA); LOADROW(whB1, Whh1, gB, sB);
    LOADROW(whA2, Whh2, gA, sA); LOADROW(whB2, Whh2, gB, sB);
    LOADROW(wiA1, Wih1, gA, sA); LOADROW(wiB1, Wih1, gB, sB);
    LOADROW(wiA2, Wih2, gA, sA); LOADROW(wiB2, Wih2, gB, sB);
#pragma unroll
    for (int k = 0; k < 5; ++k) {
        wxA[k] = Wih0[gA * 5 + k] * sA;
        wxB[k] = Wih0[gB * 5 + k] * sB;
    }
    const float b0A = (bih0[gA] + bhh0[gA]) * sA;
    const float b0B = (bih0[gB] + bhh0[gB]) * sB;
    const float b1A = (bih1[gA] + bhh1[gA]) * sA;
    const float b1B = (bih1[gB] + bhh1[gB]) * sB;
    const float b2A = (bih2[gA] + bhh2[gA]) * sA;
    const float b2B = (bih2[gB] + bhh2[gB]) * sB;

    // ---- recurrent state (distributed: lane j holds h[j]; both halves) ----
    float h0d = 0.f, h1d = 0.f, h2d = 0.f;
    float c0 = 0.f, c1 = 0.f, c2 = 0.f;

    // x[s=0] prefetch: all lanes same address -> L1 broadcast
    const float* xb = x + (size_t)b * 5;
    float xv0 = xb[0], xv1 = xb[1], xv2 = xb[2], xv3 = xb[3], xv4 = xb[4];

    for (int t = 0; t < S_LEN + 2; ++t) {
        // accumulators (pre-scaled bias)
        float a0A = b0A, a0B = b0B;
        float a1A = b1A, a1B = b1B;
        float a2A = b2A, a2B = b2B;

        // layer-0 x input (K=5, values in regs)
        a0A += wxA[0] * xv0; a0B += wxB[0] * xv0;
        a0A += wxA[1] * xv1; a0B += wxB[1] * xv1;
        a0A += wxA[2] * xv2; a0B += wxB[2] * xv2;
        a0A += wxA[3] * xv3; a0B += wxB[3] * xv3;
        a0A += wxA[4] * xv4; a0B += wxB[4] * xv4;

        // fused gate dots for all 3 layers; every h-broadcast serves two uses
#pragma unroll
        for (int k = 0; k < HID; ++k) {
            float h0k = bcast(h0d, k);
            float h1k = bcast(h1d, k);
            float h2k = bcast(h2d, k);
            a0A += whA0[k] * h0k; a0B += whB0[k] * h0k;   // layer0 recurrent
            a1A += wiA1[k] * h0k; a1B += wiB1[k] * h0k;   // layer1 input
            a1A += whA1[k] * h1k; a1B += whB1[k] * h1k;   // layer1 recurrent
            a2A += wiA2[k] * h1k; a2B += wiB2[k] * h1k;   // layer2 input
            a2A += whA2[k] * h2k; a2B += whB2[k] * h2k;   // layer2 recurrent
        }

        // tails (independent chains; commits guarded by UNIFORM t-branches)
        float cn, hn;
        lstm_tail(a2A, a2B, lowHalf, c2, cn, hn);
        if (t >= 2) {
            c2 = cn; h2d = hn;
            if (lowHalf)
                hseq[((size_t)(t - 2) * BATCH + b) * HID + j] = hn;
        }
        lstm_tail(a1A, a1B, lowHalf, c1, cn, hn);
        if (t >= 1 && t < S_LEN + 1) { c1 = cn; h1d = hn; }
        lstm_tail(a0A, a0B, lowHalf, c0, cn, hn);
        if (t < S_LEN) {
            c0 = cn; h0d = hn;
            if (t + 1 < S_LEN) {    // prefetch next x, hidden by next tick
                const float* xn = xb + (size_t)(t + 1) * BATCH * 5;
                xv0 = xn[0]; xv1 = xn[1]; xv2 = xn[2]; xv3 = xn[3]; xv4 = xn[4];
            }
        }
    }
}

// MLP head: per (s,b): y = relu(w3 . (W2 (W1 h + b1) + b2) + b3)
__global__ __launch_bounds__(256)
void mlp_kernel(const float* __restrict__ h, const float* __restrict__ w1,
                const float* __restrict__ b1, const float* __restrict__ w2,
                const float* __restrict__ b2, const float* __restrict__ w3,
                const float* __restrict__ b3, float* __restrict__ out)
{
    __shared__ float W1[HID * HID];
    __shared__ float W2[HID * HID];
    __shared__ float W3[HID];
    __shared__ float B1[HID];
    __shared__ float B2[HID];
    __shared__ float B3s;

    for (int i = threadIdx.x; i < HID * HID; i += blockDim.x) {
        W1[i] = w1[i];
        W2[i] = w2[i];
    }
    if (threadIdx.x < HID) {
        W3[threadIdx.x] = w3[threadIdx.x];
        B1[threadIdx.x] = b1[threadIdx.x];
        B2[threadIdx.x] = b2[threadIdx.x];
    }
    if (threadIdx.x == 0) B3s = b3[0];
    __syncthreads();

    const size_t e = (size_t)blockIdx.x * blockDim.x + threadIdx.x;  // (s*B+b)
    float hv[HID];
    const float4* hp = reinterpret_cast<const float4*>(h + e * HID);
#pragma unroll
    for (int k4 = 0; k4 < HID / 4; ++k4) {
        float4 v = hp[k4];
        hv[4 * k4 + 0] = v.x;
        hv[4 * k4 + 1] = v.y;
        hv[4 * k4 + 2] = v.z;
        hv[4 * k4 + 3] = v.w;
    }

    float y1[HID];
#pragma unroll
    for (int jj = 0; jj < HID; ++jj) {
        float acc = B1[jj];
#pragma unroll
        for (int k = 0; k < HID; ++k) acc += W1[jj * HID + k] * hv[k];
        y1[jj] = acc;
    }
    float y2[HID];
#pragma unroll
    for (int jj = 0; jj < HID; ++jj) {
        float acc = B2[jj];
#pragma unroll
        for (int k = 0; k < HID; ++k) acc += W2[jj * HID + k] * y1[k];
        y2[jj] = acc;
    }
    float acc3 = B3s;
#pragma unroll
    for (int k = 0; k < HID; ++k) acc3 += W3[k] * y2[k];
    out[e] = fmaxf(acc3, 0.0f);
}

extern "C" void kernel_launch(void* const* d_in, const int* in_sizes, int n_in,
                              void* d_out, int out_size, void* d_ws, size_t ws_size,
                              hipStream_t stream)
{
    const float* x    = (const float*)d_in[0];
    const float* Wih0 = (const float*)d_in[1];
    const float* Whh0 = (const float*)d_in[2];
    const float* bih0 = (const float*)d_in[3];
    const float* bhh0 = (const float*)d_in[4];
    const float* Wih1 = (const float*)d_in[5];
    const float* Whh1 = (const float*)d_in[6];
    const float* bih1 = (const float*)d_in[7];
    const float* bhh1 = (const float*)d_in[8];
    const float* Wih2 = (const float*)d_in[9];
    const float* Whh2 = (const float*)d_in[10];
    const float* bih2 = (const float*)d_in[11];
    const float* bhh2 = (const float*)d_in[12];
    const float* w1   = (const float*)d_in[13];
    const float* b1   = (const float*)d_in[14];
    const float* w2   = (const float*)d_in[15];
    const float* b2   = (const float*)d_in[16];
    const float* w3   = (const float*)d_in[17];
    const float* b3   = (const float*)d_in[18];

    // [S, BATCH, HID] fp32 buffer (64 MB) for layer-2 output
    float* hseq = (float*)d_ws;

    lstm3_fused<<<BATCH, 64, 0, stream>>>(x, Wih0, Whh0, bih0, bhh0,
                                          Wih1, Whh1, bih1, bhh1,
                                          Wih2, Whh2, bih2, bhh2, hseq);

    mlp_kernel<<<(S_LEN * BATCH) / 256, 256, 0, stream>>>(hseq, w1, b1, w2, b2, w3, b3,
                                                          (float*)d_out);
}